// Round 4
// baseline (209.801 us; speedup 1.0000x reference)
//
#include <hip/hip_runtime.h>
#include <hip/hip_bf16.h>

// Problem constants
#define BATCH   4096
#define HIDDEN  128
#define SESS    50
#define KTOT    4096
#define NB      ((size_t)BATCH * HIDDEN)

// GEMM tiling: block = 32 rows x 128 cols x K-half (2048); BK=128 per LDS tile.
#define BK      128
#define NT      16                   // tiles per k-half (2048/128)
#define ABYTES  16384                // 32 rows * 128 k * 4B
#define BBYTES  32768                // 128 k * 128 cols * 2B
#define BUF     (ABYTES + BBYTES)    // 49152; x3 buffers = 147456 B LDS

typedef __bf16 bf16x8 __attribute__((ext_vector_type(8)));
typedef __bf16 bf16x4 __attribute__((ext_vector_type(4)));
typedef float  f32x4  __attribute__((ext_vector_type(4)));
typedef float  f32x2  __attribute__((ext_vector_type(2)));

__device__ __forceinline__ f32x4 mfma_bf16(bf16x8 a, bf16x8 b, f32x4 c) {
    return __builtin_amdgcn_mfma_f32_16x16x32_bf16(a, b, c, 0, 0, 0);
}

// Async global->LDS, 16B/lane. LDS dest = wave-uniform base (+lane*16 by HW);
// global src is per-lane (swizzles live on the source side). Tracked by vmcnt.
__device__ __forceinline__ void gload16(const void* g, void* l) {
    __builtin_amdgcn_global_load_lds(
        (const __attribute__((address_space(1))) void*)g,
        (__attribute__((address_space(3))) void*)l, 16, 0, 0);
}

// Packed B layout (BYTES), XOR-swizzled for conflict-free ds_read_b128:
//   elem(k,h) -> (k>>3)*2048 + [ (h>>4)*256 + (h&15)*16 + (k&7)*2 ] ^ (((k>>3)&3)<<4)
// Tile-local chunk c = ks*4+quad, global chunk G = kh*256 + t*16 + c -> G&3 == quad.
// A-tile LDS: [32 rows][512B]; within-row byte w holds global byte w ^ ((row&7)<<4).

// ---------------------------------------------------------------------------
// Gather: E[b][h] = sum_s emb[items[b][s]][h] -> packed bf16 ETp (layout above).
// ---------------------------------------------------------------------------
__global__ __launch_bounds__(256)
void gather_sum_kernel(const float* __restrict__ emb,
                       const int* __restrict__ items32,
                       __bf16* __restrict__ ETp) {
    __shared__ int sidx[4][SESS];
    const int t  = threadIdx.x;
    const int b0 = blockIdx.x * 4;
    const bool is64 = (items32[1] | items32[3] | items32[5] | items32[7] |
                       items32[9] | items32[11] | items32[13] | items32[15]) == 0;
    if (t < 4 * SESS) {
        const int w_ = t / SESS, s_ = t % SESS;
        sidx[w_][s_] = is64
            ? (int)((const long long*)items32)[(long)(b0 + w_) * SESS + s_]
            : items32[(b0 + w_) * SESS + s_];
    }
    __syncthreads();
    const int w    = t >> 6;
    const int lane = t & 63;
    const int c    = lane & 31;
    const int h    = lane >> 5;
    f32x4 acc = {0.f, 0.f, 0.f, 0.f};
#pragma unroll
    for (int i = 0; i < 25; ++i) {
        acc += *(const f32x4*)(emb + (long)sidx[w][h + 2 * i] * HIDDEN + c * 4);
    }
#pragma unroll
    for (int j = 0; j < 4; ++j) acc[j] += __shfl_xor(acc[j], 32, 64);
    if (h == 0) {
        const int  b     = b0 + w;
        const long chunk = b >> 3;
        const int  swz   = (int)((chunk & 3) << 4);
        char* basep = (char*)ETp + chunk * 2048 + (b & 7) * 2;
        const int hi4 = (c >> 2) * 256;          // (h>>4)*256
#pragma unroll
        for (int j = 0; j < 4; ++j) {
            const int hl = 4 * (c & 3) + j;      // h&15
            *(__bf16*)(basep + ((hi4 + hl * 16) ^ swz)) = (__bf16)acc[j];
        }
    }
}

// ---------------------------------------------------------------------------
// GEMM v6 (k-split, B-reuse x4): partial[kh] = X[32r x k-half] @ Bpk[k-half x 128].
// grid (128,2) x 256thr. Per BK=128 tile: A 16KB + B 32KB staged via
// global_load_lds (12 ops/wave), triple-buffered, depth-2 prefetch, counted
// vmcnt(24/12/0), raw s_barrier. K-loop pure ds_read+cvt+MFMA.
// Wave w: rows (w&1)*16..+15, cols (w>>1)*64..+63 (4 n-frags) -> acc[4].
// C/D layout: row = quad*4 + reg, col = lane&15 [HW-verified m89/m91].
// Output: plain fp32 row-major partial at Tpart + kh*NB (reduce kernels pack).
// ---------------------------------------------------------------------------
__global__ __launch_bounds__(256, 1)
void gemm_mfma_kernel(const float* __restrict__ X,
                      const __bf16* __restrict__ Bpk,
                      float* __restrict__ Tpart) {
    __shared__ __align__(16) char lds[3 * BUF];   // 147456 B
    const int tid  = threadIdx.x;
    const int w    = tid >> 6;
    const int lane = tid & 63;
    const int lo   = lane & 15;
    const int quad = lane >> 4;
    const int rowBase = blockIdx.x * 32;
    const int kh      = blockIdx.y;               // k-half

    // staging: wave w -> A ops {4w..4w+3} (2 rows each), B ops {8w..8w+7}
#define STAGE(t_, dst_) do {                                                 \
    _Pragma("unroll")                                                        \
    for (int ai_ = 0; ai_ < 4; ++ai_) {                                      \
        const int i_    = 4 * w + ai_;                                       \
        const int rloc_ = 2 * i_ + (lane >> 5);                              \
        gload16((const char*)X +                                             \
                    ((size_t)(rowBase + rloc_) * KTOT + kh * 2048 +          \
                     (size_t)(t_) * BK) * 4 +                                \
                    (((lane & 31) * 16) ^ ((rloc_ & 7) << 4)),               \
                (dst_) + i_ * 1024);                                         \
    }                                                                        \
    _Pragma("unroll")                                                        \
    for (int bi_ = 0; bi_ < 8; ++bi_) {                                      \
        const int j_ = 8 * w + bi_;                                          \
        gload16((const char*)Bpk + (size_t)kh * 524288 +                     \
                    (size_t)(t_) * BBYTES + j_ * 1024 + lane * 16,           \
                (dst_) + ABYTES + j_ * 1024);                                \
    }                                                                        \
} while (0)

    f32x4 acc[4];
#pragma unroll
    for (int i = 0; i < 4; ++i) acc[i] = (f32x4){0.f, 0.f, 0.f, 0.f};

    const int rbase = (w & 1) * 16;     // wave's row-frag
    const int ntb   = (w >> 1) * 4;     // wave's first n-frag
    const int akey  = (lo & 7) << 4;    // ((rbase+lo)&7)<<4, rbase%16==0
    const int bkey  = quad << 4;

#define KTILE(cb_) do {                                                      \
    const char* Ar_ = (cb_) + (rbase + lo) * 512;                            \
    const char* Bb_ = (cb_) + ABYTES + quad * 2048;                          \
    _Pragma("unroll")                                                        \
    for (int ks_ = 0; ks_ < 4; ++ks_) {                                      \
        const f32x4 a0_ =                                                    \
            *(const f32x4*)(Ar_ + ((ks_ * 128 + quad * 32) ^ akey));         \
        const f32x4 a1_ =                                                    \
            *(const f32x4*)(Ar_ + ((ks_ * 128 + quad * 32 + 16) ^ akey));    \
        bf16x8 af_;                                                          \
        af_[0] = (__bf16)a0_[0]; af_[1] = (__bf16)a0_[1];                    \
        af_[2] = (__bf16)a0_[2]; af_[3] = (__bf16)a0_[3];                    \
        af_[4] = (__bf16)a1_[0]; af_[5] = (__bf16)a1_[1];                    \
        af_[6] = (__bf16)a1_[2]; af_[7] = (__bf16)a1_[3];                    \
        _Pragma("unroll")                                                    \
        for (int j_ = 0; j_ < 4; ++j_) {                                     \
            const bf16x8 b_ = *(const bf16x8*)(Bb_ + ks_ * 8192 +            \
                (((ntb + j_) * 256 + lo * 16) ^ bkey));                      \
            acc[j_] = mfma_bf16(af_, b_, acc[j_]);                           \
        }                                                                    \
    }                                                                        \
} while (0)

    // prologue: tiles 0,1 in flight (24 vmem ops/wave)
    STAGE(0, lds);
    STAGE(1, lds + BUF);

    char* cb = lds;               // compute buffer (tile t)
    char* sb = lds + 2 * BUF;     // stage buffer   (tile t+2)
    for (int t = 0; t < NT; ++t) {
        if (t + 2 < NT) STAGE(t + 2, sb);
        if (t < NT - 2)
            asm volatile("s_waitcnt vmcnt(24)" ::: "memory");
        else if (t == NT - 2)
            asm volatile("s_waitcnt vmcnt(12)" ::: "memory");
        else
            asm volatile("s_waitcnt vmcnt(0)" ::: "memory");
        __builtin_amdgcn_s_barrier();        // all waves' tile-t staging done
        __builtin_amdgcn_sched_barrier(0);
        KTILE(cb);
        __builtin_amdgcn_s_barrier();        // reads done before restage
        __builtin_amdgcn_sched_barrier(0);
        cb += BUF; if (cb == lds + 3 * BUF) cb = lds;
        sb += BUF; if (sb == lds + 3 * BUF) sb = lds;
    }
#undef KTILE
#undef STAGE

    // fp32 partial store: row = rbase + quad*4 + r, col = (ntb+j)*16 + lo
    float* op = Tpart + (size_t)kh * NB +
                (size_t)(rowBase + rbase) * HIDDEN;
#pragma unroll
    for (int r = 0; r < 4; ++r) {
#pragma unroll
        for (int j = 0; j < 4; ++j)
            op[(quad * 4 + r) * HIDDEN + (ntb + j) * 16 + lo] = acc[j][r];
    }
}

// ---------------------------------------------------------------------------
// reduce2: T = partial0 + partial1 -> packed bf16 TTp (gemm-B layout).
// ---------------------------------------------------------------------------
__global__ __launch_bounds__(256)
void reduce2_kernel(const float* __restrict__ Tp, __bf16* __restrict__ TTp) {
    const size_t i = ((size_t)blockIdx.x * 256 + threadIdx.x) * 4;
    f32x4 a = *(const f32x4*)(Tp + i);
    a += *(const f32x4*)(Tp + NB + i);
    const int  b     = (int)(i >> 7);
    const int  h0    = (int)(i & 127);
    const long chunk = b >> 3;
    const int  swz   = (int)((chunk & 3) << 4);
    char* basep = (char*)TTp + chunk * 2048 + (b & 7) * 2;
#pragma unroll
    for (int j = 0; j < 4; ++j) {
        const int h = h0 + j;
        *(__bf16*)(basep + (((h >> 4) * 256 + (h & 15) * 16) ^ swz)) =
            (__bf16)a[j];
    }
}

// ---------------------------------------------------------------------------
// reduce_norm: out[row] = normalize(partial0 + partial1). One wave per row,
// 2 floats/lane, 6-step shfl_xor reduce.
// ---------------------------------------------------------------------------
__global__ __launch_bounds__(256)
void reduce_norm_kernel(const float* __restrict__ Tp, float* __restrict__ out) {
    const int t    = threadIdx.x;
    const int w    = t >> 6;
    const int lane = t & 63;
    const int row  = blockIdx.x * 4 + w;
    const size_t base = (size_t)row * HIDDEN + lane * 2;
    f32x2 v = *(const f32x2*)(Tp + base);
    v += *(const f32x2*)(Tp + NB + base);
    float sq = v[0] * v[0] + v[1] * v[1];
#pragma unroll
    for (int m = 1; m < 64; m <<= 1) sq += __shfl_xor(sq, m, 64);
    const float s = rsqrtf(sq);
    f32x2 o = {v[0] * s, v[1] * s};
    *(f32x2*)(out + base) = o;
}

// ---------------------------------------------------------------------------
// out = normalize_rows( D @ (A @ E) )
// 5 dispatches: gather -> gemm(A,E) x2 partials -> reduce2 (pack TTp) ->
// gemm(D,T) x2 partials -> reduce_norm.
// ws: ETp 1MB | TTp 1MB | Tp fp32 x2 4MB  (~6 MB)
// ---------------------------------------------------------------------------
extern "C" void kernel_launch(void* const* d_in, const int* in_sizes, int n_in,
                              void* d_out, int out_size, void* d_ws, size_t ws_size,
                              hipStream_t stream) {
    const float* emb   = (const float*)d_in[0];
    const int*   items = (const int*)d_in[1];
    const float* A     = (const float*)d_in[2];
    const float* D     = (const float*)d_in[3];
    float* out = (float*)d_out;

    __bf16* ETp = (__bf16*)d_ws;
    __bf16* TTp = ETp + NB;
    float*  Tp  = (float*)(TTp + NB);

    gather_sum_kernel<<<BATCH / 4, 256, 0, stream>>>(emb, items, ETp);
    gemm_mfma_kernel<<<dim3(BATCH / 32, 2), 256, 0, stream>>>(A, ETp, Tp);
    reduce2_kernel<<<512, 256, 0, stream>>>(Tp, TTp);
    gemm_mfma_kernel<<<dim3(BATCH / 32, 2), 256, 0, stream>>>(D, TTp, Tp);
    reduce_norm_kernel<<<BATCH / 4, 256, 0, stream>>>(Tp, out);
}